// Round 3
// baseline (321.203 us; speedup 1.0000x reference)
//
#include <hip/hip_runtime.h>
#include <math.h>

#define HH 96
#define WW 96
#define CC 64
#define NH 4
#define HD 16
#define KS 13
#define NTOK (HH*WW)

// ---------------- Fused GEMM: out[TM x 64-section] = LN?(A)[TM,K] @ W[K,NC] ----
// 256 threads; per-thread RP rows x 4 cols. A staged transposed in LDS
// (pad +4 keeps float4 rows 16B-aligned), W section staged in LDS.
// Optional fused row-LayerNorm of A (K==64 only), GELU, residual, qkv-split out.
template<int TM, int K, int NC, bool LN, bool GELU_ACT, bool RESID, bool QKV_OUT>
__global__ __launch_bounds__(256) void gemm_kernel(
    const float* __restrict__ A, const float* __restrict__ W,
    const float* __restrict__ bias, const float* __restrict__ resid,
    const float* __restrict__ lng, const float* __restrict__ lnb,
    float* __restrict__ out, float* __restrict__ kvout)
{
    constexpr int RP = TM / 16;                 // rows per thread (2 or 4)
    __shared__ float Ast[64][TM + 4];           // [k][row], transposed
    __shared__ float Wst[64][64];               // [k][col]
    const int tid = threadIdx.x;
    const int t0 = blockIdx.x * TM;
    const int tc = tid & 15, tr = tid >> 4;
    const int c0 = tc * 4, r0 = tr * RP;
    const int cbase = blockIdx.y * 64;

    float acc[RP][4];
    {
        const float4 b4 = *(const float4*)&bias[cbase + c0];
        #pragma unroll
        for (int i = 0; i < RP; i++) { acc[i][0]=b4.x; acc[i][1]=b4.y; acc[i][2]=b4.z; acc[i][3]=b4.w; }
    }

    for (int k0 = 0; k0 < K; k0 += 64) {
        if (k0) __syncthreads();
        for (int i = tid; i < TM * 64; i += 256) {
            int r = i >> 6, k = i & 63;
            Ast[k][r] = A[(t0 + r) * K + k0 + k];
        }
        for (int i = tid; i < 64 * 64; i += 256) {
            int kr = i >> 6, c = i & 63;
            Wst[kr][c] = W[(k0 + kr) * NC + cbase + c];
        }
        __syncthreads();
        if (LN) {  // K==64: full row resident; 4 threads per row
            if (tid < TM * 4) {
                int lr = tid >> 2, qd = tid & 3;
                float s = 0.f, s2 = 0.f;
                #pragma unroll
                for (int j = 0; j < 16; j++) { float v = Ast[qd*16+j][lr]; s += v; s2 += v*v; }
                s  += __shfl_xor(s, 1);  s  += __shfl_xor(s, 2);
                s2 += __shfl_xor(s2, 1); s2 += __shfl_xor(s2, 2);
                float mu  = s  * (1.f/64.f);
                float var = s2 * (1.f/64.f) - mu * mu;
                float rs  = rsqrtf(var + 1e-5f);
                #pragma unroll
                for (int j = 0; j < 16; j++) {
                    int k = qd*16+j;
                    Ast[k][lr] = (Ast[k][lr] - mu) * rs * lng[k] + lnb[k];
                }
            }
            __syncthreads();
        }
        #pragma unroll
        for (int k = 0; k < 64; k++) {
            float4 w = *(const float4*)&Wst[k][c0];
            if constexpr (RP == 4) {
                float4 a = *(const float4*)&Ast[k][r0];
                float av[4] = {a.x, a.y, a.z, a.w};
                #pragma unroll
                for (int i = 0; i < 4; i++) {
                    acc[i][0] += av[i]*w.x; acc[i][1] += av[i]*w.y;
                    acc[i][2] += av[i]*w.z; acc[i][3] += av[i]*w.w;
                }
            } else {
                float2 a = *(const float2*)&Ast[k][r0];
                float av[2] = {a.x, a.y};
                #pragma unroll
                for (int i = 0; i < 2; i++) {
                    acc[i][0] += av[i]*w.x; acc[i][1] += av[i]*w.y;
                    acc[i][2] += av[i]*w.z; acc[i][3] += av[i]*w.w;
                }
            }
        }
    }

    #pragma unroll
    for (int i = 0; i < RP; i++) {
        int row = t0 + r0 + i;
        if constexpr (QKV_OUT) {
            if (blockIdx.y == 0) {  // q section, scaled by hd^-0.5
                float4 o = make_float4(acc[i][0]*0.25f, acc[i][1]*0.25f,
                                       acc[i][2]*0.25f, acc[i][3]*0.25f);
                *(float4*)&out[row * 64 + c0] = o;
            } else {                // k -> slot 0, v -> slot 1, interleaved
                int off = (blockIdx.y == 1) ? 0 : 1;
                #pragma unroll
                for (int j = 0; j < 4; j++)
                    kvout[row * 128 + (c0 + j) * 2 + off] = acc[i][j];
            }
        } else {
            float4 o = make_float4(acc[i][0], acc[i][1], acc[i][2], acc[i][3]);
            if constexpr (GELU_ACT) {
                o.x = 0.5f*o.x*(1.f+erff(o.x*0.70710678118f));
                o.y = 0.5f*o.y*(1.f+erff(o.y*0.70710678118f));
                o.z = 0.5f*o.z*(1.f+erff(o.z*0.70710678118f));
                o.w = 0.5f*o.w*(1.f+erff(o.w*0.70710678118f));
            }
            if constexpr (RESID) {
                float4 rr = *(const float4*)&resid[row * NC + cbase + c0];
                o.x += rr.x; o.y += rr.y; o.z += rr.z; o.w += rr.w;
            }
            *(float4*)&out[row * NC + cbase + c0] = o;
        }
    }
}

// ---------------- Neighborhood attention: one wave/token, single pass --------
// q: [token][64]; kv: [token][64] float2 (k,v interleaved per channel).
// Logits small (|p + bias| < ~2) -> softmax without max-shift is exact.
__global__ __launch_bounds__(256) void na_attn_kernel(
    const float* __restrict__ q, const float2* __restrict__ kv,
    const float* __restrict__ rpb, float* __restrict__ out)
{
    int wave = threadIdx.x >> 6;
    int lane = threadIdx.x & 63;
    int token = blockIdx.x * 4 + wave;
    int head = lane >> 4, dim = lane & 15;

    int y = token / WW, x = token - y * WW;
    int gh = y % 3, ih = y / 3;
    int gw = x % 3, iw = x / 3;
    int sh = ih - 6; sh = sh < 0 ? 0 : (sh > 19 ? 19 : sh);
    int sw = iw - 6; sw = sw < 0 ? 0 : (sw > 19 ? 19 : sw);

    int co = head * HD + dim;
    float qv = q[token * 64 + co];
    const float* bias_h = rpb + head * 625 + (sw - iw + 12);

    float acc = 0.f, s = 0.f;
    for (int kh = 0; kh < KS; kh++) {
        int ny = gh + 3 * (sh + kh);
        int rh = sh + kh - ih + 12;
        const float2* kp = kv + (ny * WW + gw + 3 * sw) * 64 + co;
        const float* bp = bias_h + rh * 25;
        #pragma unroll
        for (int kw = 0; kw < KS; kw++) {
            float2 kvv = kp[kw * 192];      // (k, v) of neighbor channel
            float p = qv * kvv.x;
            p += __shfl_xor(p, 1);
            p += __shfl_xor(p, 2);
            p += __shfl_xor(p, 4);
            p += __shfl_xor(p, 8);
            float e = __expf(p + bp[kw]);
            s += e;
            acc += e * kvv.y;
        }
    }
    out[token * 64 + co] = acc / s;
}

extern "C" void kernel_launch(void* const* d_in, const int* in_sizes, int n_in,
                              void* d_out, int out_size, void* d_ws, size_t ws_size,
                              hipStream_t stream) {
    const float* x       = (const float*)d_in[0];
    const float* norm1_g = (const float*)d_in[1];
    const float* norm1_b = (const float*)d_in[2];
    const float* qkv_w   = (const float*)d_in[3];
    const float* qkv_b   = (const float*)d_in[4];
    const float* rpb     = (const float*)d_in[5];
    const float* proj_w  = (const float*)d_in[6];
    const float* proj_b  = (const float*)d_in[7];
    const float* norm2_g = (const float*)d_in[8];
    const float* norm2_b = (const float*)d_in[9];
    const float* fc1_w   = (const float*)d_in[10];
    const float* fc1_b   = (const float*)d_in[11];
    const float* fc2_w   = (const float*)d_in[12];
    const float* fc2_b   = (const float*)d_in[13];
    float* out = (float*)d_out;

    float* ws = (float*)d_ws;
    float* qbuf     = ws;                      // 9216*64
    float* kvbuf    = qbuf + NTOK * 64;        // 9216*128 (k,v interleaved)
    float* attn_out = kvbuf + NTOK * 128;      // 9216*64
    float* x2       = attn_out + NTOK * 64;    // 9216*64
    float* hidden   = x2 + NTOK * 64;          // 9216*256

    dim3 blk(256);
    // 1. q/k/v = LN1(x) @ qkv_w + qkv_b  (LN fused; q scaled; kv interleaved)
    gemm_kernel<64, 64, 192, true, false, false, true>
        <<<dim3(NTOK/64, 3), blk, 0, stream>>>(x, qkv_w, qkv_b, nullptr,
                                               norm1_g, norm1_b, qbuf, kvbuf);
    // 2. neighborhood attention (single pass, float2 kv)
    na_attn_kernel<<<NTOK/4, blk, 0, stream>>>(qbuf, (const float2*)kvbuf, rpb, attn_out);
    // 3. x2 = x + attn_out @ proj_w + proj_b
    gemm_kernel<32, 64, 64, false, false, true, false>
        <<<dim3(NTOK/32, 1), blk, 0, stream>>>(attn_out, proj_w, proj_b, x,
                                               nullptr, nullptr, x2, nullptr);
    // 4. hidden = gelu(LN2(x2) @ fc1_w + fc1_b)  (LN fused)
    gemm_kernel<64, 64, 256, true, true, false, false>
        <<<dim3(NTOK/64, 4), blk, 0, stream>>>(x2, fc1_w, fc1_b, nullptr,
                                               norm2_g, norm2_b, hidden, nullptr);
    // 5. out = x2 + hidden @ fc2_w + fc2_b
    gemm_kernel<32, 256, 64, false, false, true, false>
        <<<dim3(NTOK/32, 1), blk, 0, stream>>>(hidden, fc2_w, fc2_b, x2,
                                               nullptr, nullptr, out, nullptr);
}

// Round 4
// 226.157 us; speedup vs baseline: 1.4203x; 1.4203x over previous
//
#include <hip/hip_runtime.h>
#include <math.h>

#define HH 96
#define WW 96
#define CC 64
#define NH 4
#define HD 16
#define KS 13
#define NTOK (HH*WW)

// ---------------- LayerNorm: one wave (64 lanes) per token ----------------
__global__ __launch_bounds__(256) void ln_kernel(const float* __restrict__ x,
                                                 const float* __restrict__ g,
                                                 const float* __restrict__ b,
                                                 float* __restrict__ out) {
    int wave = threadIdx.x >> 6;
    int lane = threadIdx.x & 63;
    int token = blockIdx.x * 4 + wave;
    float v = x[token * CC + lane];
    float s = v;
    #pragma unroll
    for (int o = 1; o < 64; o <<= 1) s += __shfl_xor(s, o);
    float mu = s * (1.0f / 64.0f);
    float d = v - mu;
    float s2 = d * d;
    #pragma unroll
    for (int o = 1; o < 64; o <<= 1) s2 += __shfl_xor(s2, o);
    float var = s2 * (1.0f / 64.0f);
    out[token * CC + lane] = d * rsqrtf(var + 1e-5f) * g[lane] + b[lane];
}

// ---------------- GEMM: out[M, 64-col section] = A[M,K] @ W[K,NC] + bias ------
// 256 threads; thread = (tc 0..15, tr 0..15) computes RP rows x 4 cols.
// A staged transposed in LDS (pad +4 keeps float4/float2 reads aligned),
// W streamed from global (tiny, L1/L2-resident, shared by all blocks).
// OUTMODE: 0 = plain (opt GELU/resid), 1 = qkv split (y=0: q*0.25 -> out,
//          y=1/2: k/v interleaved float2 -> kvout).
template<int TM, int K, int NC, bool GELU_ACT, bool RESID, int OUTMODE>
__global__ __launch_bounds__(256) void gemm_kernel(
    const float* __restrict__ A, const float* __restrict__ W,
    const float* __restrict__ bias, const float* __restrict__ resid,
    float* __restrict__ out, float* __restrict__ kvout)
{
    constexpr int RP = TM / 16;                // 4 (TM=64) or 2 (TM=32)
    __shared__ float Ast[64][TM + 4];          // [k][row]
    const int tid = threadIdx.x;
    const int t0 = blockIdx.x * TM;
    const int tc = tid & 15, tr = tid >> 4;
    const int c0 = tc * 4, r0 = tr * RP;
    const int cbase = blockIdx.y * 64;
    const int c = cbase + c0;

    float acc[RP][4];
    {
        const float4 b4 = *(const float4*)&bias[c];
        #pragma unroll
        for (int i = 0; i < RP; i++) { acc[i][0]=b4.x; acc[i][1]=b4.y; acc[i][2]=b4.z; acc[i][3]=b4.w; }
    }

    for (int k0 = 0; k0 < K; k0 += 64) {
        if (k0) __syncthreads();
        // coalesced global read; LDS write has 8-way conflicts but only
        // TM*64/256 store instrs/thread (16 at TM=64) -- negligible.
        for (int i = tid; i < TM * 64; i += 256) {
            int r = i >> 6, k = i & 63;
            Ast[k][r] = A[(t0 + r) * K + k0 + k];
        }
        __syncthreads();
        const float* wp = W + k0 * NC + c;
        #pragma unroll 4
        for (int k = 0; k < 64; k++) {
            float4 w = *(const float4*)&wp[k * NC];
            if constexpr (RP == 4) {
                float4 a = *(const float4*)&Ast[k][r0];
                float av[4] = {a.x, a.y, a.z, a.w};
                #pragma unroll
                for (int i = 0; i < 4; i++) {
                    acc[i][0] += av[i]*w.x; acc[i][1] += av[i]*w.y;
                    acc[i][2] += av[i]*w.z; acc[i][3] += av[i]*w.w;
                }
            } else {
                float2 a = *(const float2*)&Ast[k][r0];
                float av[2] = {a.x, a.y};
                #pragma unroll
                for (int i = 0; i < 2; i++) {
                    acc[i][0] += av[i]*w.x; acc[i][1] += av[i]*w.y;
                    acc[i][2] += av[i]*w.z; acc[i][3] += av[i]*w.w;
                }
            }
        }
    }

    #pragma unroll
    for (int i = 0; i < RP; i++) {
        int row = t0 + r0 + i;
        if constexpr (OUTMODE == 1) {
            if (blockIdx.y == 0) {   // q section: scale by hd^-0.5
                float4 o = make_float4(acc[i][0]*0.25f, acc[i][1]*0.25f,
                                       acc[i][2]*0.25f, acc[i][3]*0.25f);
                *(float4*)&out[row * 64 + c0] = o;
            } else {                 // k -> slot 0, v -> slot 1 (interleaved)
                int off = (blockIdx.y == 1) ? 0 : 1;
                #pragma unroll
                for (int j = 0; j < 4; j++)
                    kvout[row * 128 + (c0 + j) * 2 + off] = acc[i][j];
            }
        } else {
            float4 o = make_float4(acc[i][0], acc[i][1], acc[i][2], acc[i][3]);
            if constexpr (GELU_ACT) {
                o.x = 0.5f*o.x*(1.f+erff(o.x*0.70710678118f));
                o.y = 0.5f*o.y*(1.f+erff(o.y*0.70710678118f));
                o.z = 0.5f*o.z*(1.f+erff(o.z*0.70710678118f));
                o.w = 0.5f*o.w*(1.f+erff(o.w*0.70710678118f));
            }
            if constexpr (RESID) {
                float4 rr = *(const float4*)&resid[row * NC + c];
                o.x += rr.x; o.y += rr.y; o.z += rr.z; o.w += rr.w;
            }
            *(float4*)&out[row * NC + c] = o;
        }
    }
}

// ---------------- Neighborhood attention: one wave/token, single pass --------
// q: [token][64]; kv: [token][64] float2 (k,v interleaved per channel).
// Logits small (|p + bias| < ~2) -> softmax without max-shift is exact.
__global__ __launch_bounds__(256) void na_attn_kernel(
    const float* __restrict__ q, const float2* __restrict__ kv,
    const float* __restrict__ rpb, float* __restrict__ out)
{
    int wave = threadIdx.x >> 6;
    int lane = threadIdx.x & 63;
    int token = blockIdx.x * 4 + wave;
    int head = lane >> 4, dim = lane & 15;

    int y = token / WW, x = token - y * WW;
    int gh = y % 3, ih = y / 3;
    int gw = x % 3, iw = x / 3;
    int sh = ih - 6; sh = sh < 0 ? 0 : (sh > 19 ? 19 : sh);
    int sw = iw - 6; sw = sw < 0 ? 0 : (sw > 19 ? 19 : sw);

    int co = head * HD + dim;
    float qv = q[token * 64 + co];
    const float* bias_h = rpb + head * 625 + (sw - iw + 12);

    float acc = 0.f, s = 0.f;
    for (int kh = 0; kh < KS; kh++) {
        int ny = gh + 3 * (sh + kh);
        int rh = sh + kh - ih + 12;
        const float2* kp = kv + (ny * WW + gw + 3 * sw) * 64 + co;
        const float* bp = bias_h + rh * 25;
        #pragma unroll
        for (int kw = 0; kw < KS; kw++) {
            float2 kvv = kp[kw * 192];      // (k, v) of neighbor channel
            float p = qv * kvv.x;
            p += __shfl_xor(p, 1);
            p += __shfl_xor(p, 2);
            p += __shfl_xor(p, 4);
            p += __shfl_xor(p, 8);
            float e = __expf(p + bp[kw]);
            s += e;
            acc += e * kvv.y;
        }
    }
    out[token * 64 + co] = acc / s;
}

extern "C" void kernel_launch(void* const* d_in, const int* in_sizes, int n_in,
                              void* d_out, int out_size, void* d_ws, size_t ws_size,
                              hipStream_t stream) {
    const float* x       = (const float*)d_in[0];
    const float* norm1_g = (const float*)d_in[1];
    const float* norm1_b = (const float*)d_in[2];
    const float* qkv_w   = (const float*)d_in[3];
    const float* qkv_b   = (const float*)d_in[4];
    const float* rpb     = (const float*)d_in[5];
    const float* proj_w  = (const float*)d_in[6];
    const float* proj_b  = (const float*)d_in[7];
    const float* norm2_g = (const float*)d_in[8];
    const float* norm2_b = (const float*)d_in[9];
    const float* fc1_w   = (const float*)d_in[10];
    const float* fc1_b   = (const float*)d_in[11];
    const float* fc2_w   = (const float*)d_in[12];
    const float* fc2_b   = (const float*)d_in[13];
    float* out = (float*)d_out;

    float* ws = (float*)d_ws;
    float* h1       = ws;                      // 9216*64
    float* qbuf     = h1 + NTOK * 64;          // 9216*64
    float* kvbuf    = qbuf + NTOK * 64;        // 9216*128 (k,v interleaved)
    float* attn_out = kvbuf + NTOK * 128;      // 9216*64
    float* x2       = attn_out + NTOK * 64;    // 9216*64
    float* h2       = x2 + NTOK * 64;          // 9216*64
    float* hidden   = h2 + NTOK * 64;          // 9216*256

    dim3 blk(256);
    // 1. LN1
    ln_kernel<<<NTOK / 4, blk, 0, stream>>>(x, norm1_g, norm1_b, h1);
    // 2. q/k/v = h1 @ qkv_w + qkv_b  (q scaled; kv interleaved)
    gemm_kernel<64, 64, 192, false, false, 1>
        <<<dim3(NTOK/64, 3), blk, 0, stream>>>(h1, qkv_w, qkv_b, nullptr, qbuf, kvbuf);
    // 3. neighborhood attention (single pass, float2 kv)
    na_attn_kernel<<<NTOK/4, blk, 0, stream>>>(qbuf, (const float2*)kvbuf, rpb, attn_out);
    // 4. x2 = x + attn_out @ proj_w + proj_b
    gemm_kernel<32, 64, 64, false, true, 0>
        <<<dim3(NTOK/32, 1), blk, 0, stream>>>(attn_out, proj_w, proj_b, x, x2, nullptr);
    // 5. LN2
    ln_kernel<<<NTOK / 4, blk, 0, stream>>>(x2, norm2_g, norm2_b, h2);
    // 6. hidden = gelu(h2 @ fc1_w + fc1_b)
    gemm_kernel<64, 64, 256, true, false, 0>
        <<<dim3(NTOK/64, 4), blk, 0, stream>>>(h2, fc1_w, fc1_b, nullptr, hidden, nullptr);
    // 7. out = x2 + hidden @ fc2_w + fc2_b
    gemm_kernel<32, 256, 64, false, true, 0>
        <<<dim3(NTOK/32, 1), blk, 0, stream>>>(hidden, fc2_w, fc2_b, x2, out, nullptr);
}